// Round 4
// baseline (265.654 us; speedup 1.0000x reference)
//
#include <hip/hip_runtime.h>

// SSIM loss, fused. Round 4: barrier-free, LDS-free, wave-autonomous.
//  - One wave per (image, 11-row band): 96*46 = 4416 waves, grid 1104x256.
//  - Lane owns 8 consecutive cols (2 float4 loads per row per image).
//  - Vertical 7-row sliding column sums (5 quantities x 8 cols) in registers;
//    retire by re-reading the old row (L2/L3-hot; FETCH_SIZE r3 proved
//    caches absorb it). Both new-row and retire-row loads prefetched one
//    full iteration ahead -> global latency off the critical path.
//  - Horizontal 7-tap: lane needs cols 8s..8s+13 = own 8 sums + neighbor's
//    first 6, fetched via __shfl_down(.,1) (ds_bpermute: no barrier, no LDS).
//  - SSIM on raw sums (scale factors folded), v_rcp for the divide
//    (validated rounds 2-3, absmax 0.0).

#define IW    512
#define OUTW  506
#define RBAND 11          // output rows per wave; 46*11 = 506 exactly
#define NB    46
#define NIMG  96
#define NWAVE (NIMG * NB) // 4416
#define C1N2  0.2401f     // 1e-4 * 49^2
#define C2N2  2.1609f     // 9e-4 * 49^2
#define KA    (49.0f/24.0f)
#define KB    (49.0f/48.0f)
#define TOTAL_OUT 24579456.0f   // 96*506*506

__global__ void ssim_zero(float* acc) {
    if (threadIdx.x == 0) acc[0] = 0.0f;
}

__device__ __forceinline__ float ssim_raw(float Sx, float Sy, float Sxx,
                                          float Syy, float Sxy) {
    float sxsy = Sx * Sy;
    float p    = fmaf(Sx, Sx, Sy * Sy);
    float a1   = fmaf(2.0f, sxsy, C1N2);
    float b1   = p + C1N2;
    float a2   = fmaf(KA, fmaf(49.0f, Sxy, -sxsy), C2N2);
    float b2   = fmaf(KB, fmaf(49.0f, Sxx + Syy, -p), C2N2);
    return (a1 * a2) * __builtin_amdgcn_rcpf(b1 * b2);
}

__device__ __forceinline__ void acc_add(float cs[5][8],
                                        const float4& xa, const float4& xb,
                                        const float4& ya, const float4& yb) {
    float xs[8] = {xa.x, xa.y, xa.z, xa.w, xb.x, xb.y, xb.z, xb.w};
    float ys[8] = {ya.x, ya.y, ya.z, ya.w, yb.x, yb.y, yb.z, yb.w};
#pragma unroll
    for (int c = 0; c < 8; ++c) {
        cs[0][c] += xs[c];
        cs[1][c] += ys[c];
        cs[2][c] = fmaf(xs[c], xs[c], cs[2][c]);
        cs[3][c] = fmaf(ys[c], ys[c], cs[3][c]);
        cs[4][c] = fmaf(xs[c], ys[c], cs[4][c]);
    }
}

__device__ __forceinline__ void acc_sub(float cs[5][8],
                                        const float4& xa, const float4& xb,
                                        const float4& ya, const float4& yb) {
    float xs[8] = {xa.x, xa.y, xa.z, xa.w, xb.x, xb.y, xb.z, xb.w};
    float ys[8] = {ya.x, ya.y, ya.z, ya.w, yb.x, yb.y, yb.z, yb.w};
#pragma unroll
    for (int c = 0; c < 8; ++c) {
        cs[0][c] -= xs[c];
        cs[1][c] -= ys[c];
        cs[2][c] = fmaf(-xs[c], xs[c], cs[2][c]);
        cs[3][c] = fmaf(-ys[c], ys[c], cs[3][c]);
        cs[4][c] = fmaf(-xs[c], ys[c], cs[4][c]);
    }
}

__global__ __launch_bounds__(256) void ssim_main(const float* __restrict__ X,
                                                 const float* __restrict__ Y,
                                                 float* __restrict__ acc) {
    const int t  = threadIdx.x;
    const int s  = t & 63;                   // lane
    const int w  = blockIdx.x * 4 + (t >> 6);  // global wave id, 0..4415
    const int img  = w / NB;
    const int band = w % NB;
    const int r0 = band * RBAND;

    const float4* X4 = (const float4*)(X + (size_t)img * IW * IW);
    const float4* Y4 = (const float4*)(Y + (size_t)img * IW * IW);
    const int ci = 2 * s;                    // float4 index; lane cols 8s..8s+7

    float cs[5][8];
#pragma unroll
    for (int q = 0; q < 5; ++q)
#pragma unroll
        for (int c = 0; c < 8; ++c) cs[q][c] = 0.0f;

    // prime with input rows r0 .. r0+5
#pragma unroll
    for (int i = 0; i < 6; ++i) {
        const int r = r0 + i;
        float4 xa = X4[r * 128 + ci], xb = X4[r * 128 + ci + 1];
        float4 ya = Y4[r * 128 + ci], yb = Y4[r * 128 + ci + 1];
        acc_add(cs, xa, xb, ya, yb);
    }

    // prefetch for j=0: new row r0+6, retire row r0
    float4 nxa = X4[(r0 + 6) * 128 + ci], nxb = X4[(r0 + 6) * 128 + ci + 1];
    float4 nya = Y4[(r0 + 6) * 128 + ci], nyb = Y4[(r0 + 6) * 128 + ci + 1];
    float4 rxa = X4[r0 * 128 + ci],       rxb = X4[r0 * 128 + ci + 1];
    float4 rya = Y4[r0 * 128 + ci],       ryb = Y4[r0 * 128 + ci + 1];

    float accS = 0.0f;

    for (int j = 0; j < RBAND; ++j) {
        // window = rows [r0+j .. r0+j+6]: consume prefetched new row
        acc_add(cs, nxa, nxb, nya, nyb);

        // prefetch next new row (clamped; value unused on last iter)
        {
            const int rn = min(r0 + j + 7, IW - 1);
            nxa = X4[rn * 128 + ci]; nxb = X4[rn * 128 + ci + 1];
            nya = Y4[rn * 128 + ci]; nyb = Y4[rn * 128 + ci + 1];
        }

        // halo: neighbor lane's first 6 column sums, all shuffles up front
        float halo[5][6];
#pragma unroll
        for (int q = 0; q < 5; ++q)
#pragma unroll
            for (int k = 0; k < 6; ++k)
                halo[q][k] = __shfl_down(cs[q][k], 1, 64);

        // sliding 7-tap windows; m = output col offset within lane strip
        float W[5];
#pragma unroll
        for (int q = 0; q < 5; ++q)
            W[q] = ((cs[q][0] + cs[q][1]) + (cs[q][2] + cs[q][3])) +
                   ((cs[q][4] + cs[q][5]) + cs[q][6]);
        accS += ssim_raw(W[0], W[1], W[2], W[3], W[4]);          // m=0
#pragma unroll
        for (int m = 1; m < 8; ++m) {
#pragma unroll
            for (int q = 0; q < 5; ++q) {
                float cn = (m == 1) ? cs[q][7] : halo[q][m - 2];
                W[q] += cn - cs[q][m - 1];
            }
            float Sv = ssim_raw(W[0], W[1], W[2], W[3], W[4]);
            if (m < 2) accS += Sv;                               // always valid
            else       accS += (8 * s + m < OUTW) ? Sv : 0.0f;   // lane 63 tail
        }

        // retire row r0+j (prefetched), then prefetch next retire row
        acc_sub(cs, rxa, rxb, rya, ryb);
        {
            const int rr = r0 + j + 1;       // <= 506, always in-bounds
            rxa = X4[rr * 128 + ci]; rxb = X4[rr * 128 + ci + 1];
            rya = Y4[rr * 128 + ci]; ryb = Y4[rr * 128 + ci + 1];
        }
    }

    // wave-level reduce, one atomic per wave
#pragma unroll
    for (int off = 32; off > 0; off >>= 1)
        accS += __shfl_down(accS, off, 64);
    if (s == 0) atomicAdd(acc, accS);
}

__global__ void ssim_finalize(const float* __restrict__ acc,
                              float* __restrict__ out) {
    if (threadIdx.x == 0) out[0] = 1.0f - acc[0] / TOTAL_OUT;
}

extern "C" void kernel_launch(void* const* d_in, const int* in_sizes, int n_in,
                              void* d_out, int out_size, void* d_ws, size_t ws_size,
                              hipStream_t stream) {
    const float* X = (const float*)d_in[0];
    const float* Y = (const float*)d_in[1];
    float* accum = (float*)d_ws;
    float* out = (float*)d_out;

    hipLaunchKernelGGL(ssim_zero, dim3(1), dim3(64), 0, stream, accum);
    hipLaunchKernelGGL(ssim_main, dim3(NWAVE / 4), dim3(256), 0, stream,
                       X, Y, accum);
    hipLaunchKernelGGL(ssim_finalize, dim3(1), dim3(64), 0, stream, accum, out);
}

// Round 5
// 230.056 us; speedup vs baseline: 1.1547x; 1.1547x over previous
//
#include <hip/hip_runtime.h>

// SSIM loss, fused. Round 5: r3 data path at 2.5x occupancy.
//  - 256 threads (4 waves) / block, same 31.2 KB LDS -> 5 blocks x 4 waves
//    = 20 waves/CU (r3 was 10). __launch_bounds__(256,5) caps VGPR at 102.
//  - Vertical: thread owns cols 2t,2t+1 (float2 loads, 512 B/wave coalesced);
//    7-row sliding sums in regs; retire via prefetched re-read (L2/L3-hot).
//  - LDS planes swizzled word(col)=12*(col>>3)+(col&7): b64 publishes and
//    b128/b64 strip reads all at dense-access conflict baseline.
//  - Horizontal: 2 rows/iter, 2 waves per row, thread -> 4 px from 10 col
//    sums (2x b128 + 1x b64 per quantity).
//  - No atomics / no zero kernel: block partials -> d_ws, finalize reduces.

#define IW    512
#define OUTW  506
#define BAND  22          // output rows per block; 22*23 = 506 exactly
#define NBANDS 23
#define NIMG  96
#define NPART (NBANDS * NIMG)   // 2208 block partials
#define C1N2  0.2401f     // 1e-4 * 49^2
#define C2N2  2.1609f     // 9e-4 * 49^2
#define KA    (49.0f/24.0f)
#define KB    (49.0f/48.0f)
#define TOTAL_OUT 24579456.0f   // 96*506*506

__device__ __forceinline__ float ssim_raw(float Sx, float Sy, float Sxx,
                                          float Syy, float Sxy) {
    float sxsy = Sx * Sy;
    float p    = fmaf(Sx, Sx, Sy * Sy);
    float a1   = fmaf(2.0f, sxsy, C1N2);
    float b1   = p + C1N2;
    float a2   = fmaf(KA, fmaf(49.0f, Sxy, -sxsy), C2N2);
    float b2   = fmaf(KB, fmaf(49.0f, Sxx + Syy, -p), C2N2);
    return (a1 * a2) * __builtin_amdgcn_rcpf(b1 * b2);
}

__global__ __launch_bounds__(256, 5) void ssim_main(const float* __restrict__ X,
                                                    const float* __restrict__ Y,
                                                    float* __restrict__ partials) {
    // [2 rows][5 quantities][65 slots * 12 words]; slot-64 words are read-only
    // garbage consumed only by masked tail pixels.
    __shared__ float plane[2][5][65 * 12];
    __shared__ float wsum[4];

    const int t    = threadIdx.x;
    const int band = blockIdx.x;
    const int img  = blockIdx.y;
    const int r0   = band * BAND;
    const float2* X2 = (const float2*)(X + (size_t)img * IW * IW);
    const float2* Y2 = (const float2*)(Y + (size_t)img * IW * IW);
    // vertical: thread owns cols 2t, 2t+1; row stride = 256 float2

    float sxa=0,sxb=0, sya=0,syb=0, sxxa=0,sxxb=0, syya=0,syyb=0, sxya=0,sxyb=0;

#pragma unroll
    for (int i = 0; i < 6; ++i) {
        float2 x = X2[(r0 + i) * 256 + t];
        float2 y = Y2[(r0 + i) * 256 + t];
        sxa += x.x;  sxb += x.y;  sya += y.x;  syb += y.y;
        sxxa = fmaf(x.x,x.x,sxxa); sxxb = fmaf(x.y,x.y,sxxb);
        syya = fmaf(y.x,y.x,syya); syyb = fmaf(y.y,y.y,syyb);
        sxya = fmaf(x.x,y.x,sxya); sxyb = fmaf(x.y,y.y,sxyb);
    }

    const int woff = 12 * (t >> 2) + 2 * (t & 3);   // word offset of col 2t

    // horizontal mapping: 2 waves per row
    const int hw  = t >> 7;            // which of the 2 rows this iter
    const int ht  = t & 127;
    const int p0  = 4 * ht;            // first output col of this thread
    const int u   = ht >> 1;
    const int off = (ht & 1) * 4;
    const int aA = 12 * u + off;               // c[0..3]
    const int aB = 12 * u + (off ? 12 : 4);    // c[4..7]
    const int aC = 12 * u + 12 + off;          // c[8..9]

    // prefetch for j=0: new rows r0+6,r0+7; retire rows r0,r0+1
    float2 nx[2], ny[2], rx[2], ry[2];
#pragma unroll
    for (int k = 0; k < 2; ++k) {
        nx[k] = X2[(r0 + 6 + k) * 256 + t];
        ny[k] = Y2[(r0 + 6 + k) * 256 + t];
        rx[k] = X2[(r0 + k) * 256 + t];
        ry[k] = Y2[(r0 + k) * 256 + t];
    }

    float accS = 0.0f;

    for (int j = 0; j < BAND; j += 2) {
#pragma unroll
        for (int k = 0; k < 2; ++k) {
            // add new input row (prefetched) -> window rows [r0+j+k .. +6]
            float2 x = nx[k], y = ny[k];
            sxa += x.x;  sxb += x.y;  sya += y.x;  syb += y.y;
            sxxa = fmaf(x.x,x.x,sxxa); sxxb = fmaf(x.y,x.y,sxxb);
            syya = fmaf(y.x,y.x,syya); syyb = fmaf(y.y,y.y,syyb);
            sxya = fmaf(x.x,y.x,sxya); sxyb = fmaf(x.y,y.y,sxyb);
            // publish
            *(float2*)&plane[k][0][woff] = make_float2(sxa,  sxb);
            *(float2*)&plane[k][1][woff] = make_float2(sya,  syb);
            *(float2*)&plane[k][2][woff] = make_float2(sxxa, sxxb);
            *(float2*)&plane[k][3][woff] = make_float2(syya, syyb);
            *(float2*)&plane[k][4][woff] = make_float2(sxya, sxyb);
            // retire oldest row (prefetched)
            float2 ox = rx[k], oy = ry[k];
            sxa -= ox.x;  sxb -= ox.y;  sya -= oy.x;  syb -= oy.y;
            sxxa = fmaf(-ox.x,ox.x,sxxa); sxxb = fmaf(-ox.y,ox.y,sxxb);
            syya = fmaf(-oy.x,oy.x,syya); syyb = fmaf(-oy.y,oy.y,syyb);
            sxya = fmaf(-ox.x,oy.x,sxya); sxyb = fmaf(-ox.y,oy.y,sxyb);
        }
        // prefetch next iteration's rows; they fly across both barriers
        if (j + 2 < BAND) {
#pragma unroll
            for (int k = 0; k < 2; ++k) {
                nx[k] = X2[(r0 + j + 8 + k) * 256 + t];
                ny[k] = Y2[(r0 + j + 8 + k) * 256 + t];
                rx[k] = X2[(r0 + j + 2 + k) * 256 + t];
                ry[k] = Y2[(r0 + j + 2 + k) * 256 + t];
            }
        }
        __syncthreads();   // column sums visible

        // horizontal: 4 px per thread on row (r0+j+hw)
        {
            float c[5][10];
#pragma unroll
            for (int q = 0; q < 5; ++q) {
                const float* pl = plane[hw][q];
                float4 A = *(const float4*)(pl + aA);
                float4 B = *(const float4*)(pl + aB);
                float2 C = *(const float2*)(pl + aC);
                c[q][0]=A.x; c[q][1]=A.y; c[q][2]=A.z; c[q][3]=A.w;
                c[q][4]=B.x; c[q][5]=B.y; c[q][6]=B.z; c[q][7]=B.w;
                c[q][8]=C.x; c[q][9]=C.y;
            }
            float W[5];
#pragma unroll
            for (int q = 0; q < 5; ++q)
                W[q] = ((c[q][0] + c[q][1]) + (c[q][2] + c[q][3])) +
                       ((c[q][4] + c[q][5]) + c[q][6]);
            accS += (p0 < OUTW) ? ssim_raw(W[0],W[1],W[2],W[3],W[4]) : 0.0f;
#pragma unroll
            for (int m = 1; m < 4; ++m) {
#pragma unroll
                for (int q = 0; q < 5; ++q)
                    W[q] += c[q][m + 6] - c[q][m - 1];
                float Sv = ssim_raw(W[0],W[1],W[2],W[3],W[4]);
                accS += (p0 + m < OUTW) ? Sv : 0.0f;
            }
        }
        __syncthreads();   // reads done before next iteration's writes
    }

    // block reduce -> one partial per block (no atomics, no init needed)
#pragma unroll
    for (int o = 32; o > 0; o >>= 1)
        accS += __shfl_down(accS, o, 64);
    if ((t & 63) == 0) wsum[t >> 6] = accS;
    __syncthreads();
    if (t == 0)
        partials[blockIdx.y * NBANDS + blockIdx.x] =
            (wsum[0] + wsum[1]) + (wsum[2] + wsum[3]);
}

__global__ __launch_bounds__(256) void ssim_finalize(const float* __restrict__ partials,
                                                     float* __restrict__ out) {
    __shared__ float wsum[4];
    const int t = threadIdx.x;
    float v = 0.0f;
    for (int i = t; i < NPART; i += 256) v += partials[i];
#pragma unroll
    for (int o = 32; o > 0; o >>= 1)
        v += __shfl_down(v, o, 64);
    if ((t & 63) == 0) wsum[t >> 6] = v;
    __syncthreads();
    if (t == 0)
        out[0] = 1.0f - ((wsum[0] + wsum[1]) + (wsum[2] + wsum[3])) / TOTAL_OUT;
}

extern "C" void kernel_launch(void* const* d_in, const int* in_sizes, int n_in,
                              void* d_out, int out_size, void* d_ws, size_t ws_size,
                              hipStream_t stream) {
    const float* X = (const float*)d_in[0];
    const float* Y = (const float*)d_in[1];
    float* partials = (float*)d_ws;          // NPART floats (8.8 KB)
    float* out = (float*)d_out;

    hipLaunchKernelGGL(ssim_main, dim3(NBANDS, NIMG), dim3(256), 0, stream,
                       X, Y, partials);
    hipLaunchKernelGGL(ssim_finalize, dim3(1), dim3(256), 0, stream,
                       partials, out);
}

// Round 6
// 226.425 us; speedup vs baseline: 1.1733x; 1.0160x over previous
//
#include <hip/hip_runtime.h>

// SSIM loss, fused. Round 6: r5 + prefetch issued AFTER barrier1.
//  - KEY FIX: the compiler emits s_waitcnt vmcnt(0) before every s_barrier.
//    r5 issued prefetch loads immediately before __syncthreads -> the drain
//    exposed full L2/L3 latency every iteration to every wave. Now loads are
//    issued right after barrier1, so they fly in the shadow of the ~600-cyc
//    horizontal phase and the barrier2 drain is nearly free.
//  - Everything else identical to r5: 256 thr/block, 31.2 KB LDS (5 blocks,
//    20 waves/CU), float2 vertical ownership, swizzled stride-12 planes,
//    4 px/thread horizontal, block partials + reducing finalize.

#define IW    512
#define OUTW  506
#define BAND  22          // output rows per block; 22*23 = 506 exactly
#define NBANDS 23
#define NIMG  96
#define NPART (NBANDS * NIMG)   // 2208 block partials
#define C1N2  0.2401f     // 1e-4 * 49^2
#define C2N2  2.1609f     // 9e-4 * 49^2
#define KA    (49.0f/24.0f)
#define KB    (49.0f/48.0f)
#define TOTAL_OUT 24579456.0f   // 96*506*506

__device__ __forceinline__ float ssim_raw(float Sx, float Sy, float Sxx,
                                          float Syy, float Sxy) {
    float sxsy = Sx * Sy;
    float p    = fmaf(Sx, Sx, Sy * Sy);
    float a1   = fmaf(2.0f, sxsy, C1N2);
    float b1   = p + C1N2;
    float a2   = fmaf(KA, fmaf(49.0f, Sxy, -sxsy), C2N2);
    float b2   = fmaf(KB, fmaf(49.0f, Sxx + Syy, -p), C2N2);
    return (a1 * a2) * __builtin_amdgcn_rcpf(b1 * b2);
}

__global__ __launch_bounds__(256, 5) void ssim_main(const float* __restrict__ X,
                                                    const float* __restrict__ Y,
                                                    float* __restrict__ partials) {
    __shared__ float plane[2][5][65 * 12];
    __shared__ float wsum[4];

    const int t    = threadIdx.x;
    const int band = blockIdx.x;
    const int img  = blockIdx.y;
    const int r0   = band * BAND;
    const float2* X2 = (const float2*)(X + (size_t)img * IW * IW);
    const float2* Y2 = (const float2*)(Y + (size_t)img * IW * IW);

    float sxa=0,sxb=0, sya=0,syb=0, sxxa=0,sxxb=0, syya=0,syyb=0, sxya=0,sxyb=0;

#pragma unroll
    for (int i = 0; i < 6; ++i) {
        float2 x = X2[(r0 + i) * 256 + t];
        float2 y = Y2[(r0 + i) * 256 + t];
        sxa += x.x;  sxb += x.y;  sya += y.x;  syb += y.y;
        sxxa = fmaf(x.x,x.x,sxxa); sxxb = fmaf(x.y,x.y,sxxb);
        syya = fmaf(y.x,y.x,syya); syyb = fmaf(y.y,y.y,syyb);
        sxya = fmaf(x.x,y.x,sxya); sxyb = fmaf(x.y,y.y,sxyb);
    }

    const int woff = 12 * (t >> 2) + 2 * (t & 3);   // word offset of col 2t

    // horizontal mapping: 2 waves per row
    const int hw  = t >> 7;            // which of the 2 rows this iter
    const int ht  = t & 127;
    const int p0  = 4 * ht;            // first output col of this thread
    const int u   = ht >> 1;
    const int off = (ht & 1) * 4;
    const int aA = 12 * u + off;               // c[0..3]
    const int aB = 12 * u + (off ? 12 : 4);    // c[4..7]
    const int aC = 12 * u + 12 + off;          // c[8..9]

    // prefetch for j=0: new rows r0+6,r0+7; retire rows r0,r0+1
    float2 nx[2], ny[2], rx[2], ry[2];
#pragma unroll
    for (int k = 0; k < 2; ++k) {
        nx[k] = X2[(r0 + 6 + k) * 256 + t];
        ny[k] = Y2[(r0 + 6 + k) * 256 + t];
        rx[k] = X2[(r0 + k) * 256 + t];
        ry[k] = Y2[(r0 + k) * 256 + t];
    }

    float accS = 0.0f;

    for (int j = 0; j < BAND; j += 2) {
#pragma unroll
        for (int k = 0; k < 2; ++k) {
            // add new input row (prefetched) -> window rows [r0+j+k .. +6]
            float2 x = nx[k], y = ny[k];
            sxa += x.x;  sxb += x.y;  sya += y.x;  syb += y.y;
            sxxa = fmaf(x.x,x.x,sxxa); sxxb = fmaf(x.y,x.y,sxxb);
            syya = fmaf(y.x,y.x,syya); syyb = fmaf(y.y,y.y,syyb);
            sxya = fmaf(x.x,y.x,sxya); sxyb = fmaf(x.y,y.y,sxyb);
            // publish
            *(float2*)&plane[k][0][woff] = make_float2(sxa,  sxb);
            *(float2*)&plane[k][1][woff] = make_float2(sya,  syb);
            *(float2*)&plane[k][2][woff] = make_float2(sxxa, sxxb);
            *(float2*)&plane[k][3][woff] = make_float2(syya, syyb);
            *(float2*)&plane[k][4][woff] = make_float2(sxya, sxyb);
            // retire oldest row (prefetched)
            float2 ox = rx[k], oy = ry[k];
            sxa -= ox.x;  sxb -= ox.y;  sya -= oy.x;  syb -= oy.y;
            sxxa = fmaf(-ox.x,ox.x,sxxa); sxxb = fmaf(-ox.y,ox.y,sxxb);
            syya = fmaf(-oy.x,oy.x,syya); syyb = fmaf(-oy.y,oy.y,syyb);
            sxya = fmaf(-ox.x,oy.x,sxya); sxyb = fmaf(-ox.y,oy.y,sxyb);
        }
        __syncthreads();   // barrier1: column sums visible (drains only the
                           // lgkm DS writes — no global loads outstanding)

        // NOW issue next iteration's loads: they fly across the entire
        // horizontal phase and are drained (nearly complete) at barrier2.
        if (j + 2 < BAND) {
#pragma unroll
            for (int k = 0; k < 2; ++k) {
                nx[k] = X2[(r0 + j + 8 + k) * 256 + t];
                ny[k] = Y2[(r0 + j + 8 + k) * 256 + t];
                rx[k] = X2[(r0 + j + 2 + k) * 256 + t];
                ry[k] = Y2[(r0 + j + 2 + k) * 256 + t];
            }
        }

        // horizontal: 4 px per thread on row (r0+j+hw)
        {
            float c[5][10];
#pragma unroll
            for (int q = 0; q < 5; ++q) {
                const float* pl = plane[hw][q];
                float4 A = *(const float4*)(pl + aA);
                float4 B = *(const float4*)(pl + aB);
                float2 C = *(const float2*)(pl + aC);
                c[q][0]=A.x; c[q][1]=A.y; c[q][2]=A.z; c[q][3]=A.w;
                c[q][4]=B.x; c[q][5]=B.y; c[q][6]=B.z; c[q][7]=B.w;
                c[q][8]=C.x; c[q][9]=C.y;
            }
            float W[5];
#pragma unroll
            for (int q = 0; q < 5; ++q)
                W[q] = ((c[q][0] + c[q][1]) + (c[q][2] + c[q][3])) +
                       ((c[q][4] + c[q][5]) + c[q][6]);
            accS += (p0 < OUTW) ? ssim_raw(W[0],W[1],W[2],W[3],W[4]) : 0.0f;
#pragma unroll
            for (int m = 1; m < 4; ++m) {
#pragma unroll
                for (int q = 0; q < 5; ++q)
                    W[q] += c[q][m + 6] - c[q][m - 1];
                float Sv = ssim_raw(W[0],W[1],W[2],W[3],W[4]);
                accS += (p0 + m < OUTW) ? Sv : 0.0f;
            }
        }
        __syncthreads();   // barrier2: drains the prefetches ~600 cyc after
                           // issue (mostly complete) + guards plane reuse
    }

    // block reduce -> one partial per block (no atomics, no init needed)
#pragma unroll
    for (int o = 32; o > 0; o >>= 1)
        accS += __shfl_down(accS, o, 64);
    if ((t & 63) == 0) wsum[t >> 6] = accS;
    __syncthreads();
    if (t == 0)
        partials[blockIdx.y * NBANDS + blockIdx.x] =
            (wsum[0] + wsum[1]) + (wsum[2] + wsum[3]);
}

__global__ __launch_bounds__(256) void ssim_finalize(const float* __restrict__ partials,
                                                     float* __restrict__ out) {
    __shared__ float wsum[4];
    const int t = threadIdx.x;
    float v = 0.0f;
    for (int i = t; i < NPART; i += 256) v += partials[i];
#pragma unroll
    for (int o = 32; o > 0; o >>= 1)
        v += __shfl_down(v, o, 64);
    if ((t & 63) == 0) wsum[t >> 6] = v;
    __syncthreads();
    if (t == 0)
        out[0] = 1.0f - ((wsum[0] + wsum[1]) + (wsum[2] + wsum[3])) / TOTAL_OUT;
}

extern "C" void kernel_launch(void* const* d_in, const int* in_sizes, int n_in,
                              void* d_out, int out_size, void* d_ws, size_t ws_size,
                              hipStream_t stream) {
    const float* X = (const float*)d_in[0];
    const float* Y = (const float*)d_in[1];
    float* partials = (float*)d_ws;          // NPART floats (8.8 KB)
    float* out = (float*)d_out;

    hipLaunchKernelGGL(ssim_main, dim3(NBANDS, NIMG), dim3(256), 0, stream,
                       X, Y, partials);
    hipLaunchKernelGGL(ssim_finalize, dim3(1), dim3(256), 0, stream,
                       partials, out);
}